// Round 3
// baseline (833.102 us; speedup 1.0000x reference)
//
#include <hip/hip_runtime.h>
#include <stdint.h>

#define B_ 64
#define T_ 2000
#define QD 1024
#define MD 512
#define AD 128
#define NF 32
#define KW 31
#define TT 32
#define NCHUNK 63   // ceil(2000/32)

typedef short bf16x8 __attribute__((ext_vector_type(8)));
typedef float f32x4 __attribute__((ext_vector_type(4)));

__device__ __forceinline__ unsigned short f2bf(float f) {
    union { float f; uint32_t u; } v; v.f = f;
    uint32_t u = v.u;
    uint32_t r = u + 0x7FFFu + ((u >> 16) & 1u);   // RTNE
    return (unsigned short)(r >> 16);
}

__device__ __forceinline__ float fast_tanhf(float x) {
    x = fminf(15.f, fmaxf(-15.f, x));
    float e = __expf(2.f * x);
    return __fdividef(e - 1.f, e + 1.f);
}

// ---------------- prep: pq = tanh(query @ Wq), pack Wm -> bf16 B-frags ---------
__global__ __launch_bounds__(128) void prep_kernel(
    const float* __restrict__ query, const float* __restrict__ Wq,
    const float* __restrict__ Wm,
    float* __restrict__ pq_ws, unsigned short* __restrict__ wmp)
{
    int blk = blockIdx.x;
    int tid = threadIdx.x;
    if (blk < B_) {
        // one block per b; thread a computes dot(query[b,:], Wq[:,a])
        float a0 = 0.f, a1 = 0.f, a2 = 0.f, a3 = 0.f;
        const float* q = query + blk * QD;
        for (int d = 0; d < QD; d += 4) {
            a0 += q[d + 0] * Wq[(d + 0) * AD + tid];
            a1 += q[d + 1] * Wq[(d + 1) * AD + tid];
            a2 += q[d + 2] * Wq[(d + 2) * AD + tid];
            a3 += q[d + 3] * Wq[(d + 3) * AD + tid];
        }
        pq_ws[blk * AD + tid] = fast_tanhf((a0 + a1) + (a2 + a3));
    } else {
        // pack Wm[k][n] (512x128) into B-frag order:
        // B-frag: n = lane&15, k = (lane>>4)*8 + j   (lane = q*16+c)
        int kt = blk - B_;            // 0..15
        int nt = tid >> 4, c = tid & 15;
        for (int q = 0; q < 4; ++q)
            for (int j = 0; j < 8; ++j) {
                int k = kt * 32 + q * 8 + j;
                int n = nt * 16 + c;
                wmp[(((kt * 8 + nt) * 64) + q * 16 + c) * 8 + j] = f2bf(Wm[k * AD + n]);
            }
    }
}

// ---------------- fused energy + unnormalized context partials ------------------
union SmemTail {
    float convs[TT][NF];                              // pre-MFMA phase
    struct { float epart[TT][4]; float pex[TT]; } e;  // post-MFMA phase
};

__global__ __launch_bounds__(256, 2) void energy_kernel(
    const float* __restrict__ mem, const float* __restrict__ awc,
    const float* __restrict__ kern, const float* __restrict__ Wloc,
    const float* __restrict__ V, const float* __restrict__ pq_ws,
    const unsigned short* __restrict__ wmp,
    float* __restrict__ p_ws, float* __restrict__ Lpart, float* __restrict__ out_ctx)
{
    const int chunk = blockIdx.x, b = blockIdx.y;
    const int t0 = chunk * TT;
    const int tid = threadIdx.x;
    const int lane = tid & 63, wave = tid >> 6;

    __shared__ float aw_s[2][64];                       // awc slice [c][t0-15 .. t0+46]
    __shared__ float base_s[TT][AD + 4];                // pq + ploc
    __shared__ unsigned short apack[2][16][64][8];      // A-frags: [mt][kt][lane][j]
    __shared__ SmemTail st;

    // --- stage awc slice ---
    if (tid < 128) {
        int c = tid >> 6, xi = tid & 63;
        if (xi < TT + 30) {
            int x = t0 - 15 + xi;
            aw_s[c][xi] = (x >= 0 && x < T_) ? awc[(b * 2 + c) * T_ + x] : 0.f;
        }
    }

    // --- stage mem tile -> bf16 A-frag-packed LDS (zero for tail rows) ---
    {
        const float* mrow = mem + (size_t)b * T_ * MD;
        #pragma unroll
        for (int i = 0; i < 16; ++i) {
            int linear = i * 256 + tid;          // float4 index over [32][128]
            int tl = linear >> 7;
            int d = (linear & 127) * 4;
            float4 v = make_float4(0.f, 0.f, 0.f, 0.f);
            int t = t0 + tl;
            if (t < T_) v = *(const float4*)(mrow + (size_t)t * MD + d);
            int mt = tl >> 4, m = tl & 15, kt = d >> 5, q = (d & 31) >> 3, j = d & 7;
            unsigned short* dst = &apack[mt][kt][q * 16 + m][j];
            ushort4 pk = make_ushort4(f2bf(v.x), f2bf(v.y), f2bf(v.z), f2bf(v.w));
            *(ushort4*)dst = pk;
        }
    }
    __syncthreads();

    // --- conv: convs[t][f] = sum_{k,c} aw[c][t+k] * kern[k][c][f] (XLA cross-corr) ---
    #pragma unroll
    for (int i = 0; i < 4; ++i) {
        int idx = i * 256 + tid;     // 32*32 = 1024
        int t = idx >> 5, f = idx & 31;
        float s = 0.f;
        for (int k = 0; k < KW; ++k) {
            s += aw_s[0][t + k] * kern[(k * 2 + 0) * NF + f];
            s += aw_s[1][t + k] * kern[(k * 2 + 1) * NF + f];
        }
        st.convs[t][f] = s;
    }
    __syncthreads();

    // --- base[t][a] = pq[b][a] + tanh(conv[t,:] @ Wloc[:,a]) ---
    #pragma unroll
    for (int i = 0; i < 16; ++i) {
        int idx = i * 256 + tid;      // 32*128 = 4096
        int t = idx >> 7, a = idx & 127;
        float s = 0.f;
        #pragma unroll
        for (int f = 0; f < NF; ++f) s += st.convs[t][f] * Wloc[f * AD + a];
        base_s[t][a] = pq_ws[b * AD + a] + fast_tanhf(s);
    }
    __syncthreads();

    // --- MFMA K-loop: pm_pre[t][a] = memtile @ Wm (bf16, fp32 accum) ---
    f32x4 acc[2][2] = {};             // [mt][ntl]
    const int nt0 = wave * 2;
    for (int kt = 0; kt < 16; ++kt) {
        bf16x8 b0 = *(const bf16x8*)(wmp + (((kt * 8 + nt0 + 0) * 64) + lane) * 8);
        bf16x8 b1 = *(const bf16x8*)(wmp + (((kt * 8 + nt0 + 1) * 64) + lane) * 8);
        bf16x8 a0 = *(const bf16x8*)(&apack[0][kt][lane][0]);
        bf16x8 a1 = *(const bf16x8*)(&apack[1][kt][lane][0]);
        acc[0][0] = __builtin_amdgcn_mfma_f32_16x16x32_bf16(a0, b0, acc[0][0], 0, 0, 0);
        acc[0][1] = __builtin_amdgcn_mfma_f32_16x16x32_bf16(a0, b1, acc[0][1], 0, 0, 0);
        acc[1][0] = __builtin_amdgcn_mfma_f32_16x16x32_bf16(a1, b0, acc[1][0], 0, 0, 0);
        acc[1][1] = __builtin_amdgcn_mfma_f32_16x16x32_bf16(a1, b1, acc[1][1], 0, 0, 0);
    }

    // --- epilogue: e_t = sum_a tanh(base + tanh(pm_pre)) * V[a] ---
    //     (THE FIX: reference is tanh(pq + ploc + tanh(mem@Wm)) — pm is tanh'd
    //      BEFORE the outer sum+tanh. R1/R2 both omitted the inner tanh.)
    {
        const int q = lane >> 4, cidx = lane & 15;
        #pragma unroll
        for (int mt = 0; mt < 2; ++mt) {
            #pragma unroll
            for (int r = 0; r < 4; ++r) {
                int tl = mt * 16 + q * 4 + r;
                float s = 0.f;
                #pragma unroll
                for (int ntl = 0; ntl < 2; ++ntl) {
                    int a = (nt0 + ntl) * 16 + cidx;
                    float pm = fast_tanhf(acc[mt][ntl][r]);          // inner tanh
                    s += fast_tanhf(base_s[tl][a] + pm) * V[a];      // outer tanh
                }
                s += __shfl_xor(s, 1);
                s += __shfl_xor(s, 2);
                s += __shfl_xor(s, 4);
                s += __shfl_xor(s, 8);
                if (cidx == 0) st.e.epart[tl][wave] = s;
            }
        }
    }
    __syncthreads();

    // --- p = exp(e) (|e| <= sum|V| ~ 9, no max-subtraction needed), chunk L ---
    if (tid < TT) {
        float e = st.e.epart[tid][0] + st.e.epart[tid][1] +
                  st.e.epart[tid][2] + st.e.epart[tid][3];
        float pv = (t0 + tid < T_) ? __expf(e) : 0.f;
        st.e.pex[tid] = pv;
        p_ws[b * (NCHUNK * TT) + t0 + tid] = pv;
        float Ls = pv;
        Ls += __shfl_xor(Ls, 1);  Ls += __shfl_xor(Ls, 2);
        Ls += __shfl_xor(Ls, 4);  Ls += __shfl_xor(Ls, 8);
        Ls += __shfl_xor(Ls, 16);
        if (tid == 0) Lpart[b * NCHUNK + chunk] = Ls;
    }
    __syncthreads();

    // --- unnormalized context partial (re-read L2-hot fp32 tile) ---
    {
        const float* mrow = mem + ((size_t)b * T_ + t0) * MD;
        int nvalid = min(TT, T_ - t0);
        float c0 = 0.f, c1 = 0.f;
        for (int tl = 0; tl < nvalid; ++tl) {
            float w = st.e.pex[tl];
            c0 += w * mrow[(size_t)tl * MD + tid];
            c1 += w * mrow[(size_t)tl * MD + tid + 256];
        }
        atomicAdd(&out_ctx[b * MD + tid], c0);
        atomicAdd(&out_ctx[b * MD + tid + 256], c1);
    }
}

// ---------------- finalize: L = sum, scale ctx in-place, write weights ----------
__global__ __launch_bounds__(256) void finalize_kernel(
    const float* __restrict__ p_ws, const float* __restrict__ Lpart,
    float* __restrict__ out)
{
    int b = blockIdx.x, tid = threadIdx.x;
    __shared__ float Ls[64];
    __shared__ float invL_s;
    if (tid < 64) Ls[tid] = (tid < NCHUNK) ? Lpart[b * NCHUNK + tid] : 0.f;
    __syncthreads();
    if (tid == 0) {
        float L = 0.f;
        for (int i = 0; i < 64; ++i) L += Ls[i];
        invL_s = 1.f / L;
    }
    __syncthreads();
    float invL = invL_s;
    out[b * MD + tid] *= invL;
    out[b * MD + tid + 256] *= invL;
    float* wout = out + B_ * MD + b * T_;
    const float* prow = p_ws + b * (NCHUNK * TT);
    for (int t = tid; t < T_; t += 256) wout[t] = prow[t] * invL;
}

extern "C" void kernel_launch(void* const* d_in, const int* in_sizes, int n_in,
                              void* d_out, int out_size, void* d_ws, size_t ws_size,
                              hipStream_t stream) {
    const float* query  = (const float*)d_in[0];
    const float* memory = (const float*)d_in[1];
    const float* awc    = (const float*)d_in[2];
    const float* Wq     = (const float*)d_in[3];
    const float* Wm     = (const float*)d_in[4];
    const float* kern   = (const float*)d_in[5];
    const float* Wloc   = (const float*)d_in[6];
    const float* V      = (const float*)d_in[7];
    float* out = (float*)d_out;

    char* ws = (char*)d_ws;
    float* pq_ws        = (float*)ws;                              // 32 KB
    unsigned short* wmp = (unsigned short*)(ws + 32768);           // 128 KB
    float* p_ws         = (float*)(ws + 32768 + 131072);           // 64*2016*4 = 516 KB
    float* Lpart        = (float*)(ws + 32768 + 131072 + B_ * NCHUNK * TT * 4);

    // context region of d_out accumulates unnormalized partials -> must start at 0
    hipMemsetAsync(d_out, 0, B_ * MD * sizeof(float), stream);

    prep_kernel<<<B_ + 16, 128, 0, stream>>>(query, Wq, Wm, pq_ws, wmp);
    energy_kernel<<<dim3(NCHUNK, B_), 256, 0, stream>>>(
        memory, awc, kern, Wloc, V, pq_ws, wmp, p_ws, Lpart, out);
    finalize_kernel<<<B_, 256, 0, stream>>>(p_ws, Lpart, out);
}

// Round 4
// 704.904 us; speedup vs baseline: 1.1819x; 1.1819x over previous
//
#include <hip/hip_runtime.h>
#include <stdint.h>

#define B_ 64
#define T_ 2000
#define QD 1024
#define MD 512
#define AD 128
#define NF 32
#define KW 31
#define TT 16
#define NCHT 125    // total chunks (125*16 == 2000)
#define NCH 5       // chunks per block
#define GPB 25      // block-groups per batch row (25*5 == 125)

typedef short bf16x8 __attribute__((ext_vector_type(8)));
typedef float f32x4 __attribute__((ext_vector_type(4)));

// s_waitcnt imm: vmcnt[3:0]|[15:14], expcnt[6:4]=7 (no wait), lgkmcnt[11:8]
#define WAITCNT(vm, lgkm) (((vm) & 15) | (7 << 4) | (((lgkm) & 15) << 8) | (((vm) >> 4) << 14))

__device__ __forceinline__ unsigned short f2bf(float f) {
    union { float f; uint32_t u; } v; v.f = f;
    uint32_t u = v.u;
    return (unsigned short)((u + 0x7FFFu + ((u >> 16) & 1u)) >> 16);
}

__device__ __forceinline__ uint32_t pkbf(float a, float b) {
    union { float f; uint32_t u; } x, y; x.f = a; y.f = b;
    uint32_t ra = (x.u + 0x7FFFu + ((x.u >> 16) & 1u)) >> 16;
    uint32_t rb = (y.u + 0x7FFFu + ((y.u >> 16) & 1u)) & 0xFFFF0000u;
    return ra | rb;
}

__device__ __forceinline__ float fast_tanhf(float x) {
    x = fminf(15.f, fmaxf(-15.f, x));
    float e = __expf(2.f * x);
    return __fdividef(e - 1.f, e + 1.f);
}

// async 16B-per-lane DMA: LDS dest is wave-uniform base + lane*16
__device__ __forceinline__ void dma16(const float* src, void* lds_dst) {
    __builtin_amdgcn_global_load_lds(
        (const __attribute__((address_space(1))) void*)src,
        (__attribute__((address_space(3))) void*)lds_dst, 16, 0, 0);
}

// stage one 16x512 fp32 tile, xor-granule-swizzled: LDS slot (row, g) holds src granule g^row
__device__ __forceinline__ void stage_tile(const float* __restrict__ rowbase,
                                           void* lds_base, int wave, int lane) {
    #pragma unroll
    for (int s8 = 0; s8 < 8; ++s8) {
        int seg = wave * 8 + s8;                     // 32 segments of 1KB
        int row = seg >> 1;
        int gsrc = (((seg & 1) << 6) | lane) ^ row;  // permutes within the segment
        dma16(rowbase + row * MD + gsrc * 4, (char*)lds_base + seg * 1024);
    }
}

// ---------------- prep1: pq partials (k-split) + pack Wm,Wloc to bf16 frags ----
__global__ __launch_bounds__(128) void prep1_kernel(
    const float* __restrict__ query, const float* __restrict__ Wq,
    const float* __restrict__ Wm, const float* __restrict__ Wloc,
    float* __restrict__ pqpart, unsigned short* __restrict__ wmp,
    unsigned short* __restrict__ wlp)
{
    int blk = blockIdx.x, tid = threadIdx.x;
    if (blk < 512) {                       // pq partial: b = blk>>3, k-slice = blk&7
        int b = blk >> 3, sl = blk & 7;
        const float* qq = query + b * QD + sl * 128;
        const float* wq = Wq + (size_t)(sl * 128) * AD + tid;
        float s = 0.f;
        #pragma unroll 4
        for (int d = 0; d < 128; ++d) s += qq[d] * wq[(size_t)d * AD];
        pqpart[(b * 8 + sl) * AD + tid] = s;
    } else if (blk < 528) {                // Wm -> B-frag pack (validated R3)
        int kt = blk - 512;
        int nt = tid >> 4, c = tid & 15;
        for (int q = 0; q < 4; ++q)
            for (int j = 0; j < 8; ++j)
                wmp[(((kt * 8 + nt) * 64) + q * 16 + c) * 8 + j] =
                    f2bf(Wm[(kt * 32 + q * 8 + j) * AD + nt * 16 + c]);
    } else {                               // Wloc -> B-frag pack (K=32, one kt)
        int nt = tid >> 4, c = tid & 15;
        for (int q = 0; q < 4; ++q)
            for (int j = 0; j < 8; ++j)
                wlp[((nt * 64) + q * 16 + c) * 8 + j] =
                    f2bf(Wloc[(q * 8 + j) * AD + nt * 16 + c]);
    }
}

// ---------------- prep2: pq = tanh(sum of partials) ----------------------------
__global__ __launch_bounds__(256) void prep2_kernel(
    const float* __restrict__ pqpart, float* __restrict__ pq_ws)
{
    int idx = blockIdx.x * 256 + threadIdx.x;      // 8192 = 64*128
    int b = idx >> 7, a = idx & 127;
    float s = 0.f;
    #pragma unroll
    for (int sl = 0; sl < 8; ++sl) s += pqpart[(b * 8 + sl) * AD + a];
    pq_ws[idx] = fast_tanhf(s);
}

// ---------------- energy: pipelined DMA staging + MFMA + softmax + context -----
__global__ __launch_bounds__(256, 2) void energy_kernel(
    const float* __restrict__ mem, const float* __restrict__ awc,
    const float* __restrict__ kern, const float* __restrict__ V,
    const float* __restrict__ pq_ws,
    const unsigned short* __restrict__ wmp, const unsigned short* __restrict__ wlp,
    float* __restrict__ p_ws, float* __restrict__ Lpart, float* __restrict__ ctxpart)
{
    const int g = blockIdx.x, b = blockIdx.y;
    const int tid = threadIdx.x, lane = tid & 63, wave = tid >> 6;
    const int c0 = g * NCH;
    const int q = lane >> 4, cx = lane & 15;
    const int nt0 = wave * 2;

    __shared__ float mem_s[2][TT][MD];         // 64KB, swizzled granules
    __shared__ float aw_s[2][TT + KW - 1];     // 46 per channel
    __shared__ unsigned short apl[64][8];      // conv A-frag (bf16)
    __shared__ float epart[TT][4];
    __shared__ float pex[TT];

    const float* memb = mem + (size_t)b * T_ * MD;

    // chunk-invariant per-lane data
    const float pq0 = pq_ws[b * AD + nt0 * 16 + cx];
    const float pq1 = pq_ws[b * AD + (nt0 + 1) * 16 + cx];
    const float v0 = V[nt0 * 16 + cx];
    const float v1 = V[(nt0 + 1) * 16 + cx];
    const bf16x8 wl0 = *(const bf16x8*)(wlp + ((nt0 + 0) * 64 + lane) * 8);
    const bf16x8 wl1 = *(const bf16x8*)(wlp + ((nt0 + 1) * 64 + lane) * 8);

    float ctx0 = 0.f, ctx1 = 0.f;

    // prologue: prefetch tiles 0 and 1
    stage_tile(memb + (size_t)(c0 + 0) * TT * MD, &mem_s[0][0][0], wave, lane);
    stage_tile(memb + (size_t)(c0 + 1) * TT * MD, &mem_s[1][0][0], wave, lane);

    for (int i = 0; i < NCH; ++i) {
        const int cb = i & 1;
        const int t0 = (c0 + i) * TT;

        // B1: tile i ready (keep tile i+1's 8 DMA loads in flight)
        if (i + 1 < NCH) __builtin_amdgcn_s_waitcnt(WAITCNT(8, 0));
        else             __builtin_amdgcn_s_waitcnt(WAITCNT(0, 0));
        __builtin_amdgcn_s_barrier();

        // stage attention-weight slice
        if (tid < 2 * (TT + KW - 1)) {
            int ch = tid / (TT + KW - 1), xi = tid % (TT + KW - 1);
            int x = t0 - (KW / 2) + xi;
            aw_s[ch][xi] = (x >= 0 && x < T_) ? awc[(b * 2 + ch) * T_ + x] : 0.f;
        }
        __builtin_amdgcn_s_waitcnt(WAITCNT(63, 0));
        __builtin_amdgcn_s_barrier();   // B2

        // conv -> bf16 A-frag (two t's per thread share f -> kern loads reused)
        {
            int f = tid & 31, tA = tid >> 5, tB = tA + 8;
            float sA = 0.f, sB = 0.f;
            #pragma unroll
            for (int k = 0; k < KW; ++k) {
                float k0 = kern[(k * 2 + 0) * NF + f];
                float k1 = kern[(k * 2 + 1) * NF + f];
                sA = fmaf(aw_s[0][tA + k], k0, sA);
                sA = fmaf(aw_s[1][tA + k], k1, sA);
                sB = fmaf(aw_s[0][tB + k], k0, sB);
                sB = fmaf(aw_s[1][tB + k], k1, sB);
            }
            apl[(f >> 3) * 16 + tA][f & 7] = f2bf(sA);
            apl[(f >> 3) * 16 + tB][f & 7] = f2bf(sB);
        }
        __builtin_amdgcn_s_waitcnt(WAITCNT(63, 0));
        __builtin_amdgcn_s_barrier();   // B3

        // MFMA: ploc (1 kt) + pm (16 kt), A from swizzled fp32 LDS -> bf16 regs
        f32x4 accl0 = {}, accl1 = {}, accm0 = {}, accm1 = {};
        {
            bf16x8 af = *(const bf16x8*)(&apl[lane][0]);
            accl0 = __builtin_amdgcn_mfma_f32_16x16x32_bf16(af, wl0, accl0, 0, 0, 0);
            accl1 = __builtin_amdgcn_mfma_f32_16x16x32_bf16(af, wl1, accl1, 0, 0, 0);
        }
        {
            const float* tb = &mem_s[cb][0][0];
            #pragma unroll
            for (int kt = 0; kt < 16; ++kt) {
                int gr0 = kt * 8 + 2 * q;
                float4 x0 = *(const float4*)(tb + (cx * 128 + ((gr0 + 0) ^ cx)) * 4);
                float4 x1 = *(const float4*)(tb + (cx * 128 + ((gr0 + 1) ^ cx)) * 4);
                union { bf16x8 v; uint32_t w[4]; } u;
                u.w[0] = pkbf(x0.x, x0.y); u.w[1] = pkbf(x0.z, x0.w);
                u.w[2] = pkbf(x1.x, x1.y); u.w[3] = pkbf(x1.z, x1.w);
                bf16x8 b0 = *(const bf16x8*)(wmp + (((kt * 8 + nt0 + 0) * 64) + lane) * 8);
                bf16x8 b1 = *(const bf16x8*)(wmp + (((kt * 8 + nt0 + 1) * 64) + lane) * 8);
                accm0 = __builtin_amdgcn_mfma_f32_16x16x32_bf16(u.v, b0, accm0, 0, 0, 0);
                accm1 = __builtin_amdgcn_mfma_f32_16x16x32_bf16(u.v, b1, accm1, 0, 0, 0);
            }
        }

        // epilogue: e_t = sum_a tanh(pq + tanh(ploc) + tanh(pm)) * V[a]
        #pragma unroll
        for (int r = 0; r < 4; ++r) {
            int tl = q * 4 + r;
            float s = fast_tanhf(pq0 + fast_tanhf(accl0[r]) + fast_tanhf(accm0[r])) * v0
                    + fast_tanhf(pq1 + fast_tanhf(accl1[r]) + fast_tanhf(accm1[r])) * v1;
            s += __shfl_xor(s, 1);
            s += __shfl_xor(s, 2);
            s += __shfl_xor(s, 4);
            s += __shfl_xor(s, 8);
            if (cx == 0) epart[tl][wave] = s;
        }
        __builtin_amdgcn_s_waitcnt(WAITCNT(63, 0));
        __builtin_amdgcn_s_barrier();   // B4

        // p = exp(e)  (|e| <= sum|V| ~ 9: no max-subtraction needed)
        if (tid < TT) {
            float e = epart[tid][0] + epart[tid][1] + epart[tid][2] + epart[tid][3];
            float pv = __expf(e);
            pex[tid] = pv;
            p_ws[b * T_ + t0 + tid] = pv;
            float Ls = pv;
            Ls += __shfl_xor(Ls, 1);
            Ls += __shfl_xor(Ls, 2);
            Ls += __shfl_xor(Ls, 4);
            Ls += __shfl_xor(Ls, 8);
            if (tid == 0) Lpart[b * NCHT + c0 + i] = Ls;
        }
        __builtin_amdgcn_s_waitcnt(WAITCNT(63, 0));
        __builtin_amdgcn_s_barrier();   // B5

        // context accumulation straight from the swizzled fp32 LDS tile
        {
            const float* tb = &mem_s[cb][0][0];
            int g0 = tid >> 2, g1 = (tid + 256) >> 2, sub = tid & 3;
            #pragma unroll
            for (int tl = 0; tl < TT; ++tl) {
                float w = pex[tl];
                ctx0 = fmaf(w, tb[(tl * 128 + (g0 ^ tl)) * 4 + sub], ctx0);
                ctx1 = fmaf(w, tb[(tl * 128 + (g1 ^ tl)) * 4 + sub], ctx1);
            }
        }
        __builtin_amdgcn_s_waitcnt(WAITCNT(63, 0));
        __builtin_amdgcn_s_barrier();   // B6: everyone done reading buf cb

        if (i + 2 < NCH)
            stage_tile(memb + (size_t)(c0 + i + 2) * TT * MD, &mem_s[cb][0][0], wave, lane);
    }

    // one non-atomic partial store per block
    float* cp = ctxpart + (size_t)(b * GPB + g) * MD;
    cp[tid] = ctx0;
    cp[tid + 256] = ctx1;
}

// ---------------- finalize: L, scale ctx, write weights ------------------------
__global__ __launch_bounds__(256) void finalize_kernel(
    const float* __restrict__ p_ws, const float* __restrict__ Lpart,
    const float* __restrict__ ctxpart, float* __restrict__ out)
{
    int part = blockIdx.x, b = blockIdx.y, tid = threadIdx.x;
    __shared__ float ws4[4];
    float s = (tid < NCHT) ? Lpart[b * NCHT + tid] : 0.f;
    s += __shfl_xor(s, 1);  s += __shfl_xor(s, 2);
    s += __shfl_xor(s, 4);  s += __shfl_xor(s, 8);
    s += __shfl_xor(s, 16); s += __shfl_xor(s, 32);
    if ((tid & 63) == 0) ws4[tid >> 6] = s;
    __syncthreads();
    float invL = 1.f / (ws4[0] + ws4[1] + ws4[2] + ws4[3]);
    if (part == 4) {
        float c0 = 0.f, c1 = 0.f;
        for (int gg = 0; gg < GPB; ++gg) {
            const float* cp = ctxpart + (size_t)(b * GPB + gg) * MD;
            c0 += cp[tid];
            c1 += cp[tid + 256];
        }
        out[b * MD + tid] = c0 * invL;
        out[b * MD + tid + 256] = c1 * invL;
    } else {
        int t0 = part * 500;
        for (int t = t0 + tid; t < t0 + 500; t += 256)
            out[B_ * MD + b * T_ + t] = p_ws[b * T_ + t] * invL;
    }
}

extern "C" void kernel_launch(void* const* d_in, const int* in_sizes, int n_in,
                              void* d_out, int out_size, void* d_ws, size_t ws_size,
                              hipStream_t stream) {
    const float* query  = (const float*)d_in[0];
    const float* memory = (const float*)d_in[1];
    const float* awc    = (const float*)d_in[2];
    const float* Wq     = (const float*)d_in[3];
    const float* Wm     = (const float*)d_in[4];
    const float* kern   = (const float*)d_in[5];
    const float* Wloc   = (const float*)d_in[6];
    const float* V      = (const float*)d_in[7];
    float* out = (float*)d_out;

    char* ws = (char*)d_ws;
    float*          pqpart = (float*)(ws + 0);             // 64*8*128*4 = 262144
    float*          pq_ws  = (float*)(ws + 262144);        // 32768
    unsigned short* wmp    = (unsigned short*)(ws + 294912);  // 131072
    unsigned short* wlp    = (unsigned short*)(ws + 425984);  // 8192
    float*          p_ws   = (float*)(ws + 434176);        // 512000
    float*          Lpart  = (float*)(ws + 946176);        // 32000
    float*          ctxp   = (float*)(ws + 978176);        // 64*25*512*4 = 3276800

    prep1_kernel<<<529, 128, 0, stream>>>(query, Wq, Wm, Wloc, pqpart, wmp, wlp);
    prep2_kernel<<<32, 256, 0, stream>>>(pqpart, pq_ws);
    energy_kernel<<<dim3(GPB, B_), 256, 0, stream>>>(
        memory, awc, kern, V, pq_ws, wmp, wlp, p_ws, Lpart, ctxp);
    finalize_kernel<<<dim3(5, B_), 256, 0, stream>>>(p_ws, Lpart, ctxp, out);
}

// Round 5
// 508.155 us; speedup vs baseline: 1.6395x; 1.3872x over previous
//
#include <hip/hip_runtime.h>
#include <stdint.h>

#define B_ 64
#define T_ 2000
#define QD 1024
#define MD 512
#define AD 128
#define NF 32
#define KW 31
#define TT 16
#define NCHT 125    // total chunks (125*16 == 2000)
#define NCH 5       // chunks per block
#define GPB 25      // block-groups per batch row (25*5 == 125)

typedef short bf16x8 __attribute__((ext_vector_type(8)));
typedef float f32x4 __attribute__((ext_vector_type(4)));

// s_waitcnt imm: vmcnt[3:0]|[15:14], expcnt[6:4]=7 (no wait), lgkmcnt[11:8]
#define WAITCNT(vm, lgkm) (((vm) & 15) | (7 << 4) | (((lgkm) & 15) << 8) | (((vm) >> 4) << 14))

__device__ __forceinline__ unsigned short f2bf(float f) {
    union { float f; uint32_t u; } v; v.f = f;
    uint32_t u = v.u;
    return (unsigned short)((u + 0x7FFFu + ((u >> 16) & 1u)) >> 16);
}

__device__ __forceinline__ uint32_t pkbf(float a, float b) {
    union { float f; uint32_t u; } x, y; x.f = a; y.f = b;
    uint32_t ra = (x.u + 0x7FFFu + ((x.u >> 16) & 1u)) >> 16;
    uint32_t rb = (y.u + 0x7FFFu + ((y.u >> 16) & 1u)) & 0xFFFF0000u;
    return ra | rb;
}

__device__ __forceinline__ float fast_tanhf(float x) {
    x = fminf(15.f, fmaxf(-15.f, x));
    float e = __expf(2.f * x);
    return __fdividef(e - 1.f, e + 1.f);
}

// async 16B-per-lane DMA: LDS dest is wave-uniform base + lane*16
__device__ __forceinline__ void dma16(const float* src, void* lds_dst) {
    __builtin_amdgcn_global_load_lds(
        (const __attribute__((address_space(1))) void*)src,
        (__attribute__((address_space(3))) void*)lds_dst, 16, 0, 0);
}

// stage one 16x512 fp32 tile, xor-granule-swizzled: LDS slot (row, g) holds src granule g^row
__device__ __forceinline__ void stage_tile(const float* __restrict__ rowbase,
                                           void* lds_base, int wave, int lane) {
    #pragma unroll
    for (int s8 = 0; s8 < 8; ++s8) {
        int seg = wave * 8 + s8;                     // 32 segments of 1KB
        int row = seg >> 1;
        int gsrc = (((seg & 1) << 6) | lane) ^ row;  // permutes within the segment
        dma16(rowbase + row * MD + gsrc * 4, (char*)lds_base + seg * 1024);
    }
}

// ---------------- prep1: pq partials (k-split) + pack Wm,Wloc to bf16 frags ----
__global__ __launch_bounds__(128) void prep1_kernel(
    const float* __restrict__ query, const float* __restrict__ Wq,
    const float* __restrict__ Wm, const float* __restrict__ Wloc,
    float* __restrict__ pqpart, unsigned short* __restrict__ wmp,
    unsigned short* __restrict__ wlp)
{
    int blk = blockIdx.x, tid = threadIdx.x;
    if (blk < 512) {                       // pq partial: b = blk>>3, k-slice = blk&7
        int b = blk >> 3, sl = blk & 7;
        const float* qq = query + b * QD + sl * 128;
        const float* wq = Wq + (size_t)(sl * 128) * AD + tid;
        float s = 0.f;
        #pragma unroll 4
        for (int d = 0; d < 128; ++d) s += qq[d] * wq[(size_t)d * AD];
        pqpart[(b * 8 + sl) * AD + tid] = s;
    } else if (blk < 528) {                // Wm -> B-frag pack (validated R3/R4)
        int kt = blk - 512;
        int nt = tid >> 4, c = tid & 15;
        for (int q = 0; q < 4; ++q)
            for (int j = 0; j < 8; ++j)
                wmp[(((kt * 8 + nt) * 64) + q * 16 + c) * 8 + j] =
                    f2bf(Wm[(kt * 32 + q * 8 + j) * AD + nt * 16 + c]);
    } else {                               // Wloc -> B-frag pack (K=32, one kt)
        int nt = tid >> 4, c = tid & 15;
        for (int q = 0; q < 4; ++q)
            for (int j = 0; j < 8; ++j)
                wlp[((nt * 64) + q * 16 + c) * 8 + j] =
                    f2bf(Wloc[(q * 8 + j) * AD + nt * 16 + c]);
    }
}

// ---------------- conv: location features -> bf16 MFMA A-frags, all chunks -----
__global__ __launch_bounds__(256) void conv_kernel(
    const float* __restrict__ awc, const float* __restrict__ kern,
    unsigned short* __restrict__ cfrag)
{
    const int ci = blockIdx.x, b = blockIdx.y;
    const int t0 = ci * TT;
    const int tid = threadIdx.x;
    const int f = tid & 31, tA = tid >> 5, tB = tA + 8;   // two rows per thread
    const float* a0p = awc + (b * 2 + 0) * T_;
    const float* a1p = awc + (b * 2 + 1) * T_;
    float sA = 0.f, sB = 0.f;
    #pragma unroll
    for (int k = 0; k < KW; ++k) {
        float k0 = kern[(k * 2 + 0) * NF + f];
        float k1 = kern[(k * 2 + 1) * NF + f];
        int xA = t0 + tA + k - 15, xB = t0 + tB + k - 15;
        float wA0 = (xA >= 0 && xA < T_) ? a0p[xA] : 0.f;
        float wA1 = (xA >= 0 && xA < T_) ? a1p[xA] : 0.f;
        float wB0 = (xB >= 0 && xB < T_) ? a0p[xB] : 0.f;
        float wB1 = (xB >= 0 && xB < T_) ? a1p[xB] : 0.f;
        sA = fmaf(wA0, k0, sA); sA = fmaf(wA1, k1, sA);
        sB = fmaf(wB0, k0, sB); sB = fmaf(wB1, k1, sB);
    }
    // A-frag layout (validated): element j at lane q*16+m  <->  A[m][k=q*8+j], k=f
    unsigned short* base = cfrag + (size_t)(b * NCHT + ci) * 64 * 8;
    base[((f >> 3) * 16 + tA) * 8 + (f & 7)] = f2bf(sA);
    base[((f >> 3) * 16 + tB) * 8 + (f & 7)] = f2bf(sB);
}

// ---------------- energy: pipelined DMA staging + MFMA + softmax + context -----
__global__ __launch_bounds__(256, 2) void energy_kernel(
    const float* __restrict__ mem, const float* __restrict__ V,
    const float* __restrict__ pqpart,
    const unsigned short* __restrict__ wmp, const unsigned short* __restrict__ wlp,
    const unsigned short* __restrict__ cfrag,
    float* __restrict__ p_ws, float* __restrict__ Lpart, float* __restrict__ ctxpart)
{
    const int g = blockIdx.x, b = blockIdx.y;
    const int tid = threadIdx.x, lane = tid & 63, wave = tid >> 6;
    const int c0 = g * NCH;
    const int q = lane >> 4, cx = lane & 15;
    const int nt0 = wave * 2;

    __shared__ __align__(16) float mem_s[2][TT][MD];   // 64KB, swizzled granules
    __shared__ float epart[TT][4];
    __shared__ float pex[TT];

    const float* memb = mem + (size_t)b * T_ * MD;

    // finish pq here (folds prep2): pq = tanh(sum of 8 k-split partials)
    const int a0 = nt0 * 16 + cx, a1 = a0 + 16;
    float pq0a = 0.f, pq1a = 0.f;
    #pragma unroll
    for (int sl = 0; sl < 8; ++sl) {
        pq0a += pqpart[(b * 8 + sl) * AD + a0];
        pq1a += pqpart[(b * 8 + sl) * AD + a1];
    }
    const float pq0 = fast_tanhf(pq0a), pq1 = fast_tanhf(pq1a);
    const float v0 = V[a0], v1 = V[a1];
    const bf16x8 wl0 = *(const bf16x8*)(wlp + ((nt0 + 0) * 64 + lane) * 8);
    const bf16x8 wl1 = *(const bf16x8*)(wlp + ((nt0 + 1) * 64 + lane) * 8);

    // conv A-frag for chunk 0 — loaded BEFORE the DMA so vmcnt(8) at B1 covers it
    const unsigned short* cfb = cfrag + ((size_t)(b * NCHT + c0) * 64 + lane) * 8;
    bf16x8 af = *(const bf16x8*)cfb;

    float ctx0 = 0.f, ctx1 = 0.f;

    stage_tile(memb + (size_t)(c0 + 0) * TT * MD, &mem_s[0][0][0], wave, lane);
    stage_tile(memb + (size_t)(c0 + 1) * TT * MD, &mem_s[1][0][0], wave, lane);

    for (int i = 0; i < NCH; ++i) {
        const int cb = i & 1;
        const int t0 = (c0 + i) * TT;

        // B1: tile i resident (tile i+1's 8 DMA loads stay in flight)
        if (i + 1 < NCH) __builtin_amdgcn_s_waitcnt(WAITCNT(8, 0));
        else             __builtin_amdgcn_s_waitcnt(WAITCNT(0, 0));
        __builtin_amdgcn_s_barrier();

        // MFMA: ploc (1 kt, frag from regs) + pm (16 kt, unroll 4 -> no spill)
        f32x4 accl0 = {}, accl1 = {}, accm0 = {}, accm1 = {};
        accl0 = __builtin_amdgcn_mfma_f32_16x16x32_bf16(af, wl0, accl0, 0, 0, 0);
        accl1 = __builtin_amdgcn_mfma_f32_16x16x32_bf16(af, wl1, accl1, 0, 0, 0);
        {
            const float* tb = &mem_s[cb][0][0];
            #pragma unroll 4
            for (int kt = 0; kt < 16; ++kt) {
                int gr0 = kt * 8 + 2 * q;
                float4 x0 = *(const float4*)(tb + (cx * 128 + ((gr0 + 0) ^ cx)) * 4);
                float4 x1 = *(const float4*)(tb + (cx * 128 + ((gr0 + 1) ^ cx)) * 4);
                union { bf16x8 v; uint32_t w[4]; } u;
                u.w[0] = pkbf(x0.x, x0.y); u.w[1] = pkbf(x0.z, x0.w);
                u.w[2] = pkbf(x1.x, x1.y); u.w[3] = pkbf(x1.z, x1.w);
                bf16x8 b0 = *(const bf16x8*)(wmp + (((kt * 8 + nt0 + 0) * 64) + lane) * 8);
                bf16x8 b1 = *(const bf16x8*)(wmp + (((kt * 8 + nt0 + 1) * 64) + lane) * 8);
                accm0 = __builtin_amdgcn_mfma_f32_16x16x32_bf16(u.v, b0, accm0, 0, 0, 0);
                accm1 = __builtin_amdgcn_mfma_f32_16x16x32_bf16(u.v, b1, accm1, 0, 0, 0);
            }
        }

        // epilogue: e_t = sum_a tanh(pq + tanh(ploc) + tanh(pm)) * V[a]
        #pragma unroll
        for (int r = 0; r < 4; ++r) {
            int tl = q * 4 + r;
            float s = fast_tanhf(pq0 + fast_tanhf(accl0[r]) + fast_tanhf(accm0[r])) * v0
                    + fast_tanhf(pq1 + fast_tanhf(accl1[r]) + fast_tanhf(accm1[r])) * v1;
            s += __shfl_xor(s, 1);
            s += __shfl_xor(s, 2);
            s += __shfl_xor(s, 4);
            s += __shfl_xor(s, 8);
            if (cx == 0) epart[tl][wave] = s;
        }
        __builtin_amdgcn_s_waitcnt(WAITCNT(63, 0));
        __builtin_amdgcn_s_barrier();   // B2

        // p = exp(e)  (|e| <= sum|V| ~ 9: no max-subtraction needed)
        if (tid < TT) {
            float e = epart[tid][0] + epart[tid][1] + epart[tid][2] + epart[tid][3];
            float pv = __expf(e);
            pex[tid] = pv;
            p_ws[b * T_ + t0 + tid] = pv;
            float Ls = pv;
            Ls += __shfl_xor(Ls, 1);
            Ls += __shfl_xor(Ls, 2);
            Ls += __shfl_xor(Ls, 4);
            Ls += __shfl_xor(Ls, 8);
            if (tid == 0) Lpart[b * NCHT + c0 + i] = Ls;
        }
        __builtin_amdgcn_s_waitcnt(WAITCNT(63, 0));
        __builtin_amdgcn_s_barrier();   // B3

        // context accumulation straight from the swizzled fp32 LDS tile
        {
            const float* tb = &mem_s[cb][0][0];
            int g0 = tid >> 2, g1 = (tid + 256) >> 2, sub = tid & 3;
            #pragma unroll
            for (int tl = 0; tl < TT; ++tl) {
                float w = pex[tl];
                ctx0 = fmaf(w, tb[(tl * 128 + (g0 ^ tl)) * 4 + sub], ctx0);
                ctx1 = fmaf(w, tb[(tl * 128 + (g1 ^ tl)) * 4 + sub], ctx1);
            }
        }
        __builtin_amdgcn_s_waitcnt(WAITCNT(63, 0));
        __builtin_amdgcn_s_barrier();   // B4: tile cb fully consumed

        // next chunk's A-frag BEFORE the DMA burst: vmcnt(8) at B1 waits only it
        if (i + 1 < NCH) af = *(const bf16x8*)(cfb + (size_t)(i + 1) * 64 * 8);
        if (i + 2 < NCH)
            stage_tile(memb + (size_t)(c0 + i + 2) * TT * MD, &mem_s[cb][0][0], wave, lane);
    }

    // one non-atomic partial store per block
    float* cp = ctxpart + (size_t)(b * GPB + g) * MD;
    cp[tid] = ctx0;
    cp[tid + 256] = ctx1;
}

// ---------------- finalize: L, scale ctx, write weights ------------------------
__global__ __launch_bounds__(256) void finalize_kernel(
    const float* __restrict__ p_ws, const float* __restrict__ Lpart,
    const float* __restrict__ ctxpart, float* __restrict__ out)
{
    int part = blockIdx.x, b = blockIdx.y, tid = threadIdx.x;
    __shared__ float ws4[4];
    float s = (tid < NCHT) ? Lpart[b * NCHT + tid] : 0.f;
    s += __shfl_xor(s, 1);  s += __shfl_xor(s, 2);
    s += __shfl_xor(s, 4);  s += __shfl_xor(s, 8);
    s += __shfl_xor(s, 16); s += __shfl_xor(s, 32);
    if ((tid & 63) == 0) ws4[tid >> 6] = s;
    __syncthreads();
    float invL = 1.f / (ws4[0] + ws4[1] + ws4[2] + ws4[3]);
    if (part == 4) {
        float c0 = 0.f, c1 = 0.f;
        for (int gg = 0; gg < GPB; ++gg) {
            const float* cp = ctxpart + (size_t)(b * GPB + gg) * MD;
            c0 += cp[tid];
            c1 += cp[tid + 256];
        }
        out[b * MD + tid] = c0 * invL;
        out[b * MD + tid + 256] = c1 * invL;
    } else {
        int t0 = part * 500;
        for (int t = t0 + tid; t < t0 + 500; t += 256)
            out[B_ * MD + b * T_ + t] = p_ws[b * T_ + t] * invL;
    }
}

extern "C" void kernel_launch(void* const* d_in, const int* in_sizes, int n_in,
                              void* d_out, int out_size, void* d_ws, size_t ws_size,
                              hipStream_t stream) {
    const float* query  = (const float*)d_in[0];
    const float* memory = (const float*)d_in[1];
    const float* awc    = (const float*)d_in[2];
    const float* Wq     = (const float*)d_in[3];
    const float* Wm     = (const float*)d_in[4];
    const float* kern   = (const float*)d_in[5];
    const float* Wloc   = (const float*)d_in[6];
    const float* V      = (const float*)d_in[7];
    float* out = (float*)d_out;

    char* ws = (char*)d_ws;
    float*          pqpart = (float*)(ws + 0);                 // 262144
    unsigned short* wmp    = (unsigned short*)(ws + 262144);   // 131072
    unsigned short* wlp    = (unsigned short*)(ws + 393216);   // 8192
    unsigned short* cfrag  = (unsigned short*)(ws + 401408);   // 64*125*512*2 = 8192000
    float*          p_ws   = (float*)(ws + 8593408);           // 512000
    float*          Lpart  = (float*)(ws + 9105408);           // 32000
    float*          ctxp   = (float*)(ws + 9137408);           // 3276800 -> 12.4MB total

    prep1_kernel<<<529, 128, 0, stream>>>(query, Wq, Wm, Wloc, pqpart, wmp, wlp);
    conv_kernel<<<dim3(NCHT, B_), 256, 0, stream>>>(awc, kern, cfrag);
    energy_kernel<<<dim3(GPB, B_), 256, 0, stream>>>(
        memory, V, pqpart, wmp, wlp, cfrag, p_ws, Lpart, ctxp);
    finalize_kernel<<<dim3(5, B_), 256, 0, stream>>>(p_ws, Lpart, ctxp, out);
}

// Round 6
// 499.203 us; speedup vs baseline: 1.6689x; 1.0179x over previous
//
#include <hip/hip_runtime.h>
#include <stdint.h>

#define B_ 64
#define T_ 2000
#define QD 1024
#define MD 512
#define AD 128
#define NF 32
#define KW 31
#define TT 16
#define NCHT 125    // total chunks (125*16 == 2000)
#define NCH 5       // chunks per block
#define GPB 25      // block-groups per batch row (25*5 == 125)

typedef short bf16x8 __attribute__((ext_vector_type(8)));
typedef float f32x4 __attribute__((ext_vector_type(4)));

// s_waitcnt imm: vmcnt[3:0]|[15:14], expcnt[6:4]=7 (no wait), lgkmcnt[11:8]
#define WAITCNT(vm, lgkm) (((vm) & 15) | (7 << 4) | (((lgkm) & 15) << 8) | (((vm) >> 4) << 14))

__device__ __forceinline__ unsigned short f2bf(float f) {
    union { float f; uint32_t u; } v; v.f = f;
    uint32_t u = v.u;
    return (unsigned short)((u + 0x7FFFu + ((u >> 16) & 1u)) >> 16);
}

// ONE v_perm_b32: word = bf16_trunc(lo) | bf16_trunc(hi)<<16
// (S0 -> byte idx 4-7, S1 -> idx 0-3; sel 0x03020706 = [S1.b3,S1.b2,S0.b3,S0.b2])
__device__ __forceinline__ uint32_t pktrunc(float lo, float hi) {
    union { float f; uint32_t u; } a, c; a.f = lo; c.f = hi;
    return __builtin_amdgcn_perm(a.u, c.u, 0x03020706u);
}

__device__ __forceinline__ float fast_tanhf(float x) {
    x = fminf(15.f, fmaxf(-15.f, x));
    float e = __expf(2.f * x);
    return __fdividef(e - 1.f, e + 1.f);
}

// async 16B-per-lane DMA: LDS dest is wave-uniform base + lane*16
__device__ __forceinline__ void dma16(const float* src, void* lds_dst) {
    __builtin_amdgcn_global_load_lds(
        (const __attribute__((address_space(1))) void*)src,
        (__attribute__((address_space(3))) void*)lds_dst, 16, 0, 0);
}

// stage one 16x512 fp32 tile, xor-granule-swizzled: LDS slot (row, g) holds src granule g^row
__device__ __forceinline__ void stage_tile(const float* __restrict__ rowbase,
                                           void* lds_base, int wave, int lane) {
    #pragma unroll
    for (int s8 = 0; s8 < 8; ++s8) {
        int seg = wave * 8 + s8;                     // 32 segments of 1KB
        int row = seg >> 1;
        int gsrc = (((seg & 1) << 6) | lane) ^ row;  // permutes within the segment
        dma16(rowbase + row * MD + gsrc * 4, (char*)lds_base + seg * 1024);
    }
}

// ---------------- prep1: pq partials (k-split) + pack Wm,Wloc to bf16 frags ----
__global__ __launch_bounds__(128) void prep1_kernel(
    const float* __restrict__ query, const float* __restrict__ Wq,
    const float* __restrict__ Wm, const float* __restrict__ Wloc,
    float* __restrict__ pqpart, unsigned short* __restrict__ wmp,
    unsigned short* __restrict__ wlp)
{
    int blk = blockIdx.x, tid = threadIdx.x;
    if (blk < 512) {                       // pq partial: b = blk>>3, k-slice = blk&7
        int b = blk >> 3, sl = blk & 7;
        const float* qq = query + b * QD + sl * 128;
        const float* wq = Wq + (size_t)(sl * 128) * AD + tid;
        float s = 0.f;
        #pragma unroll 4
        for (int d = 0; d < 128; ++d) s += qq[d] * wq[(size_t)d * AD];
        pqpart[(b * 8 + sl) * AD + tid] = s;
    } else if (blk < 528) {                // Wm -> B-frag pack (validated R3-R5)
        int kt = blk - 512;
        int nt = tid >> 4, c = tid & 15;
        for (int q = 0; q < 4; ++q)
            for (int j = 0; j < 8; ++j)
                wmp[(((kt * 8 + nt) * 64) + q * 16 + c) * 8 + j] =
                    f2bf(Wm[(kt * 32 + q * 8 + j) * AD + nt * 16 + c]);
    } else {                               // Wloc -> B-frag pack (K=32, one kt)
        int nt = tid >> 4, c = tid & 15;
        for (int q = 0; q < 4; ++q)
            for (int j = 0; j < 8; ++j)
                wlp[((nt * 64) + q * 16 + c) * 8 + j] =
                    f2bf(Wloc[(q * 8 + j) * AD + nt * 16 + c]);
    }
}

// ---------------- conv: location features -> bf16 MFMA A-frags, all chunks -----
__global__ __launch_bounds__(256) void conv_kernel(
    const float* __restrict__ awc, const float* __restrict__ kern,
    unsigned short* __restrict__ cfrag)
{
    const int ci = blockIdx.x, b = blockIdx.y;
    const int t0 = ci * TT;
    const int tid = threadIdx.x;
    const int f = tid & 31, tA = tid >> 5, tB = tA + 8;   // two rows per thread
    const float* a0p = awc + (b * 2 + 0) * T_;
    const float* a1p = awc + (b * 2 + 1) * T_;
    float sA = 0.f, sB = 0.f;
    #pragma unroll
    for (int k = 0; k < KW; ++k) {
        float k0 = kern[(k * 2 + 0) * NF + f];
        float k1 = kern[(k * 2 + 1) * NF + f];
        int xA = t0 + tA + k - 15, xB = t0 + tB + k - 15;
        float wA0 = (xA >= 0 && xA < T_) ? a0p[xA] : 0.f;
        float wA1 = (xA >= 0 && xA < T_) ? a1p[xA] : 0.f;
        float wB0 = (xB >= 0 && xB < T_) ? a0p[xB] : 0.f;
        float wB1 = (xB >= 0 && xB < T_) ? a1p[xB] : 0.f;
        sA = fmaf(wA0, k0, sA); sA = fmaf(wA1, k1, sA);
        sB = fmaf(wB0, k0, sB); sB = fmaf(wB1, k1, sB);
    }
    unsigned short* base = cfrag + (size_t)(b * NCHT + ci) * 64 * 8;
    base[((f >> 3) * 16 + tA) * 8 + (f & 7)] = f2bf(sA);
    base[((f >> 3) * 16 + tB) * 8 + (f & 7)] = f2bf(sB);
}

// ---------------- energy: pipelined DMA staging + MFMA + softmax + context -----
__global__ __launch_bounds__(256, 2) void energy_kernel(
    const float* __restrict__ mem, const float* __restrict__ V,
    const float* __restrict__ pqpart,
    const unsigned short* __restrict__ wmp, const unsigned short* __restrict__ wlp,
    const unsigned short* __restrict__ cfrag,
    float* __restrict__ p_ws, float* __restrict__ Lpart, float* __restrict__ ctxpart)
{
    const int g = blockIdx.x, b = blockIdx.y;
    const int tid = threadIdx.x, lane = tid & 63, wave = tid >> 6;
    const int c0 = g * NCH;
    const int q = lane >> 4, cx = lane & 15;
    const int nt0 = wave * 2;

    __shared__ __align__(16) float mem_s[2][TT][MD];   // 64KB, swizzled granules
    __shared__ __align__(16) float epart[TT][4];
    __shared__ float pex[TT];

    const float* memb = mem + (size_t)b * T_ * MD;

    // pq = tanh(sum of 8 k-split partials)
    const int a0 = nt0 * 16 + cx, a1 = a0 + 16;
    float pq0a = 0.f, pq1a = 0.f;
    #pragma unroll
    for (int sl = 0; sl < 8; ++sl) {
        pq0a += pqpart[(b * 8 + sl) * AD + a0];
        pq1a += pqpart[(b * 8 + sl) * AD + a1];
    }
    const float pq0 = fast_tanhf(pq0a), pq1 = fast_tanhf(pq1a);
    const float v0 = V[a0], v1 = V[a1];
    const bf16x8 wl0 = *(const bf16x8*)(wlp + ((nt0 + 0) * 64 + lane) * 8);
    const bf16x8 wl1 = *(const bf16x8*)(wlp + ((nt0 + 1) * 64 + lane) * 8);

    const unsigned short* cfb = cfrag + ((size_t)(b * NCHT + c0) * 64 + lane) * 8;
    bf16x8 af = *(const bf16x8*)cfb;      // conv A-frag, chunk 0
    bf16x8 af_next = af;

    // context accumulator: 4 consecutive d's, half the rows (parity h)
    f32x4 ctx = {};
    const int gq = tid & 127, h = tid >> 7;

    stage_tile(memb + (size_t)(c0 + 0) * TT * MD, &mem_s[0][0][0], wave, lane);

    for (int i = 0; i < NCH; ++i) {
        const int cb = i & 1;
        const int t0c = (c0 + i) * TT;

        // B1: tile i ready (its DMA had a full chunk in flight), buf[(i+1)&1] free
        __builtin_amdgcn_s_waitcnt(WAITCNT(0, 0));
        __builtin_amdgcn_s_barrier();

        // immediately refill the just-freed buffer -> full-chunk DMA lead time
        if (i + 1 < NCH) {
            stage_tile(memb + (size_t)(c0 + i + 1) * TT * MD,
                       &mem_s[(i + 1) & 1][0][0], wave, lane);
            af_next = *(const bf16x8*)(cfb + (size_t)(i + 1) * 64 * 8);
        }

        // MFMA: ploc (1 kt, regs) + pm (16 kt; A packed via single v_perm per word)
        f32x4 accl0 = {}, accl1 = {}, accm0 = {}, accm1 = {};
        accl0 = __builtin_amdgcn_mfma_f32_16x16x32_bf16(af, wl0, accl0, 0, 0, 0);
        accl1 = __builtin_amdgcn_mfma_f32_16x16x32_bf16(af, wl1, accl1, 0, 0, 0);
        {
            const float* tb = &mem_s[cb][0][0];
            #pragma unroll 4
            for (int kt = 0; kt < 16; ++kt) {
                int gr0 = kt * 8 + 2 * q;
                float4 x0 = *(const float4*)(tb + (cx * 128 + ((gr0 + 0) ^ cx)) * 4);
                float4 x1 = *(const float4*)(tb + (cx * 128 + ((gr0 + 1) ^ cx)) * 4);
                union { bf16x8 v; uint32_t w[4]; } u;
                u.w[0] = pktrunc(x0.x, x0.y); u.w[1] = pktrunc(x0.z, x0.w);
                u.w[2] = pktrunc(x1.x, x1.y); u.w[3] = pktrunc(x1.z, x1.w);
                bf16x8 b0 = *(const bf16x8*)(wmp + (((kt * 8 + nt0 + 0) * 64) + lane) * 8);
                bf16x8 b1 = *(const bf16x8*)(wmp + (((kt * 8 + nt0 + 1) * 64) + lane) * 8);
                accm0 = __builtin_amdgcn_mfma_f32_16x16x32_bf16(u.v, b0, accm0, 0, 0, 0);
                accm1 = __builtin_amdgcn_mfma_f32_16x16x32_bf16(u.v, b1, accm1, 0, 0, 0);
            }
        }

        // epilogue: e_t = sum_a tanh(pq + tanh(ploc) + tanh(pm)) * V[a]
        #pragma unroll
        for (int r = 0; r < 4; ++r) {
            int tl = q * 4 + r;
            float s = fast_tanhf(pq0 + fast_tanhf(accl0[r]) + fast_tanhf(accm0[r])) * v0
                    + fast_tanhf(pq1 + fast_tanhf(accl1[r]) + fast_tanhf(accm1[r])) * v1;
            s += __shfl_xor(s, 1);
            s += __shfl_xor(s, 2);
            s += __shfl_xor(s, 4);
            s += __shfl_xor(s, 8);
            if (cx == 0) epart[tl][wave] = s;
        }
        __builtin_amdgcn_s_waitcnt(WAITCNT(63, 0));   // lgkm only: DMA stays in flight
        __builtin_amdgcn_s_barrier();   // B2

        // p = exp(e)  (|e| <= sum|V| ~ 9: no max-subtraction needed)
        if (tid < TT) {
            float4 ep = *(const float4*)&epart[tid][0];
            float pv = __expf(ep.x + ep.y + ep.z + ep.w);
            pex[tid] = pv;
            p_ws[b * T_ + t0c + tid] = pv;
            float Ls = pv;
            Ls += __shfl_xor(Ls, 1);
            Ls += __shfl_xor(Ls, 2);
            Ls += __shfl_xor(Ls, 4);
            Ls += __shfl_xor(Ls, 8);
            if (tid == 0) Lpart[b * NCHT + c0 + i] = Ls;
        }
        __builtin_amdgcn_s_waitcnt(WAITCNT(63, 0));
        __builtin_amdgcn_s_barrier();   // B3

        // context: float4 per thread per row-pair from the swizzled fp32 tile
        {
            const float* tb = &mem_s[cb][0][0];
            #pragma unroll
            for (int r = 0; r < 8; ++r) {
                int row = r * 2 + h;
                float w = pex[row];
                float4 m4 = *(const float4*)(tb + (row * 128 + (gq ^ row)) * 4);
                ctx.x = fmaf(w, m4.x, ctx.x);
                ctx.y = fmaf(w, m4.y, ctx.y);
                ctx.z = fmaf(w, m4.z, ctx.z);
                ctx.w = fmaf(w, m4.w, ctx.w);
            }
        }
        af = af_next;
        // no tile-consumed barrier: next B1 (after all waves' context) frees the buffer
    }

    float* cp = ctxpart + ((size_t)((b * GPB + g) * 2 + h)) * MD + gq * 4;
    *(float4*)cp = *(float4*)&ctx;
}

// ---------------- finalize: L, scale ctx, write weights ------------------------
__global__ __launch_bounds__(256) void finalize_kernel(
    const float* __restrict__ p_ws, const float* __restrict__ Lpart,
    const float* __restrict__ ctxpart, float* __restrict__ out)
{
    int part = blockIdx.x, b = blockIdx.y, tid = threadIdx.x;
    __shared__ float ws4[4];
    float s = (tid < NCHT) ? Lpart[b * NCHT + tid] : 0.f;
    s += __shfl_xor(s, 1);  s += __shfl_xor(s, 2);
    s += __shfl_xor(s, 4);  s += __shfl_xor(s, 8);
    s += __shfl_xor(s, 16); s += __shfl_xor(s, 32);
    if ((tid & 63) == 0) ws4[tid >> 6] = s;
    __syncthreads();
    float invL = 1.f / (ws4[0] + ws4[1] + ws4[2] + ws4[3]);
    if (part == 4) {
        float c0 = 0.f, c1 = 0.f;
        const float* cpb = ctxpart + (size_t)(b * GPB * 2) * MD;
        for (int gg = 0; gg < GPB * 2; ++gg) {
            const float* cp = cpb + (size_t)gg * MD;
            c0 += cp[tid];
            c1 += cp[tid + 256];
        }
        out[b * MD + tid] = c0 * invL;
        out[b * MD + tid + 256] = c1 * invL;
    } else {
        int t0 = part * 500;
        for (int t = t0 + tid; t < t0 + 500; t += 256)
            out[B_ * MD + b * T_ + t] = p_ws[b * T_ + t] * invL;
    }
}

extern "C" void kernel_launch(void* const* d_in, const int* in_sizes, int n_in,
                              void* d_out, int out_size, void* d_ws, size_t ws_size,
                              hipStream_t stream) {
    const float* query  = (const float*)d_in[0];
    const float* memory = (const float*)d_in[1];
    const float* awc    = (const float*)d_in[2];
    const float* Wq     = (const float*)d_in[3];
    const float* Wm     = (const float*)d_in[4];
    const float* kern   = (const float*)d_in[5];
    const float* Wloc   = (const float*)d_in[6];
    const float* V      = (const float*)d_in[7];
    float* out = (float*)d_out;

    char* ws = (char*)d_ws;
    float*          pqpart = (float*)(ws + 0);                 // 262144
    unsigned short* wmp    = (unsigned short*)(ws + 262144);   // 131072
    unsigned short* wlp    = (unsigned short*)(ws + 393216);   // 8192
    unsigned short* cfrag  = (unsigned short*)(ws + 401408);   // 8192000
    float*          p_ws   = (float*)(ws + 8593408);           // 512000
    float*          Lpart  = (float*)(ws + 9105408);           // 32000
    float*          ctxp   = (float*)(ws + 9137408);           // 64*25*2*512*4 = 6553600

    prep1_kernel<<<529, 128, 0, stream>>>(query, Wq, Wm, Wloc, pqpart, wmp, wlp);
    conv_kernel<<<dim3(NCHT, B_), 256, 0, stream>>>(awc, kern, cfrag);
    energy_kernel<<<dim3(GPB, B_), 256, 0, stream>>>(
        memory, V, pqpart, wmp, wlp, cfrag, p_ws, Lpart, ctxp);
    finalize_kernel<<<dim3(5, B_), 256, 0, stream>>>(p_ws, Lpart, ctxp, out);
}